// Round 10
// baseline (330.491 us; speedup 1.0000x reference)
//
#include <hip/hip_runtime.h>
#include <hip/hip_bf16.h>

#define NN 100000
#define NE 1600000
#define HID 64
#define ALPHA 0.1f
#define COEF 0.3f   // (1-ALPHA)/K

#define NBK 392            // buckets of 256 nodes: dst>>8
#define SBLK 256           // blocks for hist/scatter passes (SBLK*NBK <= NE/16 keeps runs >= 1 line)
#define EB_PER_BLK (NE / SBLK)   // 6250
#define HTOT (NBK * SBLK)        // 100352 = 98 * 1024
#define EVC 12             // per-thread register edge cache in bucketC

// hardware packed f32->bf16 (RNE), 1 VALU op for 2 values
__device__ __forceinline__ unsigned int cvtpk(float lo, float hi) {
    unsigned int r;
    asm("v_cvt_pk_bf16_f32 %0, %1, %2" : "=v"(r) : "v"(lo), "v"(hi));
    return r;
}
// lo exact bf16; hi keeps low-16-bit mantissa contamination (<=1 ulp bf16) — saves the AND
__device__ __forceinline__ void acc2(float& lo, float& hi, unsigned int u) {
    union { unsigned int i; float f; } a, b;
    a.i = u << 16; b.i = u;
    lo += a.f; hi += b.f;
}
__device__ __forceinline__ void up2(float& lo, float& hi, unsigned int u) {
    union { unsigned int i; float f; } a, b;
    a.i = u << 16; b.i = u;
    lo = a.f; hi = b.f;
}

// ---------------- bucketed CSR build (no global atomics) ----------------

__global__ void histA_kernel(const int* __restrict__ dst, int* __restrict__ hist) {
    __shared__ int cnt[NBK];
    const int b = blockIdx.x, t = threadIdx.x;
    for (int i = t; i < NBK; i += 256) cnt[i] = 0;
    __syncthreads();
    const int beg = b * EB_PER_BLK, end = beg + EB_PER_BLK;
    for (int e = beg + t; e < end; e += 256)
        atomicAdd(&cnt[dst[e] >> 8], 1);
    __syncthreads();
    for (int i = t; i < NBK; i += 256)
        hist[i * SBLK + b] = cnt[i];
}

// coalesced 2-kernel scan of hist[HTOT]
__global__ void scanHA_kernel(const int* __restrict__ hist, int* __restrict__ hsum) {
    __shared__ int red[16];
    const int b = blockIdx.x, t = threadIdx.x;
    int v = hist[b * 1024 + t];
    for (int o = 32; o > 0; o >>= 1) v += __shfl_down(v, o, 64);
    if ((t & 63) == 0) red[t >> 6] = v;
    __syncthreads();
    if (t < 64) {
        int s = (t < 16) ? red[t] : 0;
        for (int o = 8; o > 0; o >>= 1) s += __shfl_down(s, o, 64);
        if (t == 0) hsum[b] = s;
    }
}

__global__ void scanHC_kernel(int* __restrict__ hist, const int* __restrict__ hsum) {
    __shared__ int ts[1024];
    __shared__ int s_off;
    const int b = blockIdx.x, t = threadIdx.x;
    int v = hist[b * 1024 + t];
    ts[t] = v;
    if (t == 0) {
        int o = 0;
        for (int i = 0; i < b; ++i) o += hsum[i];
        s_off = o;
    }
    __syncthreads();
    for (int off = 1; off < 1024; off <<= 1) {
        int w = (t >= off) ? ts[t - off] : 0;
        __syncthreads();
        if (t >= off) ts[t] += w;
        __syncthreads();
    }
    hist[b * 1024 + t] = s_off + ((t > 0) ? ts[t - 1] : 0);
}

__global__ void scatterB_kernel(const int* __restrict__ src, const int* __restrict__ dst,
                                const int* __restrict__ hist, unsigned int* __restrict__ buck) {
    __shared__ int cur[NBK];
    const int b = blockIdx.x, t = threadIdx.x;
    for (int i = t; i < NBK; i += 256) cur[i] = hist[i * SBLK + b];
    __syncthreads();
    const int beg = b * EB_PER_BLK, end = beg + EB_PER_BLK;
    for (int e = beg + t; e < end; e += 256) {
        int d = dst[e];
        int pos = atomicAdd(&cur[d >> 8], 1);
        buck[pos] = ((unsigned int)src[e] << 8) | (unsigned int)(d & 255);
    }
}

// Per-bucket (256 nodes, 512 thr): rowptr/dinv/rdinv + csr scatter from reg-cached edges.
// csr stores src*128 (byte offset of the bf16 row).
__global__ void bucketC_kernel(const unsigned int* __restrict__ buck, const int* __restrict__ hist,
                               int* __restrict__ rowptr, float* __restrict__ dinv,
                               float* __restrict__ rdinv, int* __restrict__ csr) {
    __shared__ int cnt[256];
    __shared__ int excl[256];
    __shared__ int curs[256];
    const int j = blockIdx.x, t = threadIdx.x;
    const int ebeg = hist[j * SBLK];
    const int eend = (j == NBK - 1) ? NE : hist[(j + 1) * SBLK];
    if (t < 256) cnt[t] = 0;
    __syncthreads();
    unsigned int ev[EVC];
    int m = 0;
    for (int e = ebeg + t; e < eend; e += 512) {
        unsigned int v = buck[e];
        atomicAdd(&cnt[v & 255], 1);
        if (m < EVC) ev[m++] = v;
    }
    __syncthreads();
    if (t < 256) excl[t] = cnt[t];
    __syncthreads();
    for (int off = 1; off < 256; off <<= 1) {
        int v = (t >= off && t < 256) ? excl[t - off] : 0;
        __syncthreads();
        if (t >= off && t < 256) excl[t] += v;
        __syncthreads();
    }
    if (t < 256) {
        const int my_excl = excl[t] - cnt[t];
        const int node = j * 256 + t;
        if (node < NN) {
            rowptr[node] = ebeg + my_excl;
            float sq = (float)(cnt[t] + 1);
            float dv = rsqrtf(sq);
            dinv[node]  = dv;
            rdinv[node] = sq * dv;     // sqrt(deg+1)
        }
        curs[t] = ebeg + my_excl;
    }
    if (j == NBK - 1 && t == 0) rowptr[NN] = NE;
    __syncthreads();
    for (int i = 0; i < m; ++i) {
        unsigned int v = ev[i];
        int pos = atomicAdd(&curs[v & 255], 1);
        csr[pos] = (int)((v >> 8) << 7);          // src*128 bytes
    }
    for (int e = ebeg + t + EVC * 512; e < eend; e += 512) {
        unsigned int v = buck[e];
        int pos = atomicAdd(&curs[v & 255], 1);
        csr[pos] = (int)((v >> 8) << 7);
    }
}

// g0 = bf16(dinv[v] * x[v])
__global__ void g0_kernel(const float* __restrict__ x, const float* __restrict__ dinv,
                          unsigned short* __restrict__ g0) {
    int i = blockIdx.x * blockDim.x + threadIdx.x;
    if (i >= NN * HID / 4) return;
    float dv = dinv[(i * 4) >> 6];
    float4 v = *reinterpret_cast<const float4*>(&x[i * 4]);
    uint2 u;
    u.x = cvtpk(dv * v.x, dv * v.y);
    u.y = cvtpk(dv * v.z, dv * v.w);
    *reinterpret_cast<uint2*>(&g0[i * 4]) = u;
}

// ---------------- propagation ----------------
// One wave/node. half=lane>>5 picks edge within a pair; 32 lanes cover the 128B row
// (lane&31 -> one uint = 2 bf16 features). Reduce = single xor-32 stage, 2 accs.
template <int STEP>
__global__ void prop_kernel(const unsigned short* __restrict__ gin,
                            unsigned short* __restrict__ gout,
                            const unsigned short* __restrict__ g1,
                            const unsigned short* __restrict__ g2,
                            const float* __restrict__ x,
                            const float* __restrict__ dinv,
                            const float* __restrict__ rdinv,
                            const int* __restrict__ rowptr, const int* __restrict__ csr,
                            unsigned short* __restrict__ routb) {
    const int wid = (blockIdx.x * blockDim.x + threadIdx.x) >> 6;
    if (wid >= NN) return;
    const int lane = threadIdx.x & 63;
    const int half = lane >> 5;
    const int fb   = (lane & 31) * 4;          // byte offset within 128B row
    const int beg = rowptr[wid], endp = rowptr[wid + 1];
    const float dv = dinv[wid];
    const char* gb = (const char*)gin;
    const int ob = wid * 128 + fb;             // self-row byte offset
    const unsigned int us = *(const unsigned int*)(gb + ob);   // hoisted
    float alo = 0.f, ahi = 0.f;
    int e = beg;
    for (; e + 8 <= endp; e += 8) {            // 8 edges, 8 loads in flight
        int c0 = csr[e + half];
        int c1 = csr[e + 2 + half];
        int c2 = csr[e + 4 + half];
        int c3 = csr[e + 6 + half];
        unsigned int u0 = *(const unsigned int*)(gb + c0 + fb);
        unsigned int u1 = *(const unsigned int*)(gb + c1 + fb);
        unsigned int u2 = *(const unsigned int*)(gb + c2 + fb);
        unsigned int u3 = *(const unsigned int*)(gb + c3 + fb);
        acc2(alo, ahi, u0); acc2(alo, ahi, u1);
        acc2(alo, ahi, u2); acc2(alo, ahi, u3);
    }
    for (; e + 2 <= endp; e += 2) {
        int c = csr[e + half];
        unsigned int u = *(const unsigned int*)(gb + c + fb);
        acc2(alo, ahi, u);
    }
    if (e < endp && half == 0) {               // odd final edge
        int c = csr[e];
        unsigned int u = *(const unsigned int*)(gb + c + fb);
        acc2(alo, ahi, u);
    }
    alo += __shfl_xor(alo, 32, 64);
    ahi += __shfl_xor(ahi, 32, 64);
    if (half != 0) return;
    float slo, shi;
    up2(slo, shi, us);
    if (STEP < 2) {
        const float dv2 = dv * dv;
        unsigned int gq = cvtpk(dv2 * (alo + slo), dv2 * (ahi + shi));
        *(unsigned int*)((char*)gout + ob) = gq;
    } else {
        const float rd = rdinv[wid];           // sqrt(deg+1) = 1/dv
        unsigned int a1 = *(const unsigned int*)((const char*)g1 + ob);
        unsigned int a2 = *(const unsigned int*)((const char*)g2 + ob);
        float plo, phi, qlo, qhi;
        up2(plo, phi, a1);
        up2(qlo, qhi, a2);
        float2 xv = *reinterpret_cast<const float2*>(&x[wid * HID + (lane & 31) * 2]);
        float hlo = dv * (alo + slo), hhi = dv * (ahi + shi);
        float olo = fmaxf(fmaf(ALPHA, xv.x, COEF * fmaf(rd, plo + qlo, hlo)), 0.f);
        float ohi = fmaxf(fmaf(ALPHA, xv.y, COEF * fmaf(rd, phi + qhi, hhi)), 0.f);
        *(unsigned int*)((char*)routb + ob) = cvtpk(olo, ohi);
    }
}

// ---------------- SimpleConv(mean) of relu(out) + residual + relu ----------------
__global__ void final_kernel(const unsigned short* __restrict__ routb,
                             const float* __restrict__ x,
                             const int* __restrict__ rowptr, const int* __restrict__ csr,
                             float* __restrict__ res) {
    const int wid = (blockIdx.x * blockDim.x + threadIdx.x) >> 6;
    if (wid >= NN) return;
    const int lane = threadIdx.x & 63;
    const int half = lane >> 5;
    const int fb   = (lane & 31) * 4;
    const int beg = rowptr[wid], endp = rowptr[wid + 1];
    const char* gb = (const char*)routb;
    float alo = 0.f, ahi = 0.f;
    int e = beg;
    for (; e + 8 <= endp; e += 8) {
        int c0 = csr[e + half];
        int c1 = csr[e + 2 + half];
        int c2 = csr[e + 4 + half];
        int c3 = csr[e + 6 + half];
        unsigned int u0 = *(const unsigned int*)(gb + c0 + fb);
        unsigned int u1 = *(const unsigned int*)(gb + c1 + fb);
        unsigned int u2 = *(const unsigned int*)(gb + c2 + fb);
        unsigned int u3 = *(const unsigned int*)(gb + c3 + fb);
        acc2(alo, ahi, u0); acc2(alo, ahi, u1);
        acc2(alo, ahi, u2); acc2(alo, ahi, u3);
    }
    for (; e + 2 <= endp; e += 2) {
        int c = csr[e + half];
        unsigned int u = *(const unsigned int*)(gb + c + fb);
        acc2(alo, ahi, u);
    }
    if (e < endp && half == 0) {
        int c = csr[e];
        unsigned int u = *(const unsigned int*)(gb + c + fb);
        acc2(alo, ahi, u);
    }
    alo += __shfl_xor(alo, 32, 64);
    ahi += __shfl_xor(ahi, 32, 64);
    if (half != 0) return;
    const float inv = 1.f / fmaxf((float)(endp - beg), 1.f);
    float2 xv = *reinterpret_cast<const float2*>(&x[wid * HID + (lane & 31) * 2]);
    float2 rv;
    rv.x = fmaxf(fmaf(alo, inv, xv.x), 0.f);
    rv.y = fmaxf(fmaf(ahi, inv, xv.y), 0.f);
    *reinterpret_cast<float2*>(&res[wid * HID + (lane & 31) * 2]) = rv;
}

extern "C" void kernel_launch(void* const* d_in, const int* in_sizes, int n_in,
                              void* d_out, int out_size, void* d_ws, size_t ws_size,
                              hipStream_t stream) {
    const float* x  = (const float*)d_in[0];
    const int* ei   = (const int*)d_in[1];      // (2, NE): [src | dst]
    const int* srcp = ei;
    const int* dstp = ei + NE;
    float* resp     = (float*)d_out;

    size_t off = 0;
    auto carve = [&](size_t bytes) { size_t p = off; off = (off + bytes + 255) & ~(size_t)255; return p; };
    char* ws = (char*)d_ws;
    int*          hist   = (int*)          (ws + carve((size_t)HTOT * 4));
    int*          hsum   = (int*)          (ws + carve((size_t)128 * 4));
    unsigned int* buck   = (unsigned int*) (ws + carve((size_t)NE * 4));
    int*          rowptr = (int*)          (ws + carve((size_t)(NN + 1) * 4));
    float*        dinv   = (float*)        (ws + carve((size_t)NN * 4));
    float*        rdinv  = (float*)        (ws + carve((size_t)NN * 4));
    int*          csr    = (int*)          (ws + carve((size_t)NE * 4));
    unsigned short* gA    = (unsigned short*)(ws + carve((size_t)NN * HID * 2));
    unsigned short* gB    = (unsigned short*)(ws + carve((size_t)NN * HID * 2));
    unsigned short* gC    = (unsigned short*)(ws + carve((size_t)NN * HID * 2));
    unsigned short* routb = (unsigned short*)(ws + carve((size_t)NN * HID * 2));
    (void)ws_size; (void)n_in; (void)in_sizes; (void)out_size;

    histA_kernel<<<SBLK, 256, 0, stream>>>(dstp, hist);
    scanHA_kernel<<<HTOT / 1024, 1024, 0, stream>>>(hist, hsum);
    scanHC_kernel<<<HTOT / 1024, 1024, 0, stream>>>(hist, hsum);
    scatterB_kernel<<<SBLK, 256, 0, stream>>>(srcp, dstp, hist, buck);
    bucketC_kernel<<<NBK, 512, 0, stream>>>(buck, hist, rowptr, dinv, rdinv, csr);
    g0_kernel<<<(NN * HID / 4 + 255) / 256, 256, 0, stream>>>(x, dinv, gA);

    const int nblk = 256;                            // 4 nodes/block (1 wave each)
    const int ngrid = (NN + 3) / 4;                  // 25000
    prop_kernel<0><<<ngrid, nblk, 0, stream>>>(gA, gB, nullptr, nullptr, nullptr, dinv, rdinv, rowptr, csr, nullptr);
    prop_kernel<1><<<ngrid, nblk, 0, stream>>>(gB, gC, nullptr, nullptr, nullptr, dinv, rdinv, rowptr, csr, nullptr);
    prop_kernel<2><<<ngrid, nblk, 0, stream>>>(gC, nullptr, gB, gC, x, dinv, rdinv, rowptr, csr, routb);
    final_kernel<<<ngrid, nblk, 0, stream>>>(routb, x, rowptr, csr, resp);
}

// Round 11
// 312.041 us; speedup vs baseline: 1.0591x; 1.0591x over previous
//
#include <hip/hip_runtime.h>
#include <hip/hip_bf16.h>

#define NN 100000
#define NE 1600000
#define HID 64
#define ALPHA 0.1f
#define COEF 0.3f   // (1-ALPHA)/K

#define NBK 392            // buckets of 256 nodes: dst>>8
#define SBLK 256           // blocks for hist/scatter passes (SBLK*NBK <= NE/16 keeps runs >= 1 line)
#define EB_PER_BLK (NE / SBLK)   // 6250
#define HTOT (NBK * SBLK)        // 100352 = 98 * 1024
#define EVC 12             // per-thread register edge cache in bucketC

// hardware packed f32->bf16 (RNE), 1 VALU op for 2 values
__device__ __forceinline__ unsigned int cvtpk(float lo, float hi) {
    unsigned int r;
    asm("v_cvt_pk_bf16_f32 %0, %1, %2" : "=v"(r) : "v"(lo), "v"(hi));
    return r;
}
// lo exact bf16; hi keeps low-16-bit mantissa contamination (<=1 ulp bf16) — saves the AND
__device__ __forceinline__ void acc2(float& lo, float& hi, unsigned int u) {
    union { unsigned int i; float f; } a, b;
    a.i = u << 16; b.i = u;
    lo += a.f; hi += b.f;
}
__device__ __forceinline__ void up2(float& lo, float& hi, unsigned int u) {
    union { unsigned int i; float f; } a, b;
    a.i = u << 16; b.i = u;
    lo = a.f; hi = b.f;
}

// ---------------- bucketed CSR build (no global atomics) ----------------

__global__ void histA_kernel(const int* __restrict__ dst, int* __restrict__ hist) {
    __shared__ int cnt[NBK];
    const int b = blockIdx.x, t = threadIdx.x;
    for (int i = t; i < NBK; i += 256) cnt[i] = 0;
    __syncthreads();
    const int beg = b * EB_PER_BLK, end = beg + EB_PER_BLK;
    for (int e = beg + t; e < end; e += 256)
        atomicAdd(&cnt[dst[e] >> 8], 1);
    __syncthreads();
    for (int i = t; i < NBK; i += 256)
        hist[i * SBLK + b] = cnt[i];
}

// coalesced 2-kernel scan of hist[HTOT]
__global__ void scanHA_kernel(const int* __restrict__ hist, int* __restrict__ hsum) {
    __shared__ int red[16];
    const int b = blockIdx.x, t = threadIdx.x;
    int v = hist[b * 1024 + t];
    for (int o = 32; o > 0; o >>= 1) v += __shfl_down(v, o, 64);
    if ((t & 63) == 0) red[t >> 6] = v;
    __syncthreads();
    if (t < 64) {
        int s = (t < 16) ? red[t] : 0;
        for (int o = 8; o > 0; o >>= 1) s += __shfl_down(s, o, 64);
        if (t == 0) hsum[b] = s;
    }
}

__global__ void scanHC_kernel(int* __restrict__ hist, const int* __restrict__ hsum) {
    __shared__ int ts[1024];
    __shared__ int s_off;
    const int b = blockIdx.x, t = threadIdx.x;
    int v = hist[b * 1024 + t];
    ts[t] = v;
    if (t == 0) {
        int o = 0;
        for (int i = 0; i < b; ++i) o += hsum[i];
        s_off = o;
    }
    __syncthreads();
    for (int off = 1; off < 1024; off <<= 1) {
        int w = (t >= off) ? ts[t - off] : 0;
        __syncthreads();
        if (t >= off) ts[t] += w;
        __syncthreads();
    }
    hist[b * 1024 + t] = s_off + ((t > 0) ? ts[t - 1] : 0);
}

__global__ void scatterB_kernel(const int* __restrict__ src, const int* __restrict__ dst,
                                const int* __restrict__ hist, unsigned int* __restrict__ buck) {
    __shared__ int cur[NBK];
    const int b = blockIdx.x, t = threadIdx.x;
    for (int i = t; i < NBK; i += 256) cur[i] = hist[i * SBLK + b];
    __syncthreads();
    const int beg = b * EB_PER_BLK, end = beg + EB_PER_BLK;
    for (int e = beg + t; e < end; e += 256) {
        int d = dst[e];
        int pos = atomicAdd(&cur[d >> 8], 1);
        buck[pos] = ((unsigned int)src[e] << 8) | (unsigned int)(d & 255);
    }
}

// Per-bucket (256 nodes, 512 thr): rowptr/dinv/rdinv + csr scatter from reg-cached edges.
// csr stores src*128 (byte offset of the bf16 row).
__global__ void bucketC_kernel(const unsigned int* __restrict__ buck, const int* __restrict__ hist,
                               int* __restrict__ rowptr, float* __restrict__ dinv,
                               float* __restrict__ rdinv, int* __restrict__ csr) {
    __shared__ int cnt[256];
    __shared__ int excl[256];
    __shared__ int curs[256];
    const int j = blockIdx.x, t = threadIdx.x;
    const int ebeg = hist[j * SBLK];
    const int eend = (j == NBK - 1) ? NE : hist[(j + 1) * SBLK];
    if (t < 256) cnt[t] = 0;
    __syncthreads();
    unsigned int ev[EVC];
    int m = 0;
    for (int e = ebeg + t; e < eend; e += 512) {
        unsigned int v = buck[e];
        atomicAdd(&cnt[v & 255], 1);
        if (m < EVC) ev[m++] = v;
    }
    __syncthreads();
    if (t < 256) excl[t] = cnt[t];
    __syncthreads();
    for (int off = 1; off < 256; off <<= 1) {
        int v = (t >= off && t < 256) ? excl[t - off] : 0;
        __syncthreads();
        if (t >= off && t < 256) excl[t] += v;
        __syncthreads();
    }
    if (t < 256) {
        const int my_excl = excl[t] - cnt[t];
        const int node = j * 256 + t;
        if (node < NN) {
            rowptr[node] = ebeg + my_excl;
            float sq = (float)(cnt[t] + 1);
            float dv = rsqrtf(sq);
            dinv[node]  = dv;
            rdinv[node] = sq * dv;     // sqrt(deg+1)
        }
        curs[t] = ebeg + my_excl;
    }
    if (j == NBK - 1 && t == 0) rowptr[NN] = NE;
    __syncthreads();
    for (int i = 0; i < m; ++i) {
        unsigned int v = ev[i];
        int pos = atomicAdd(&curs[v & 255], 1);
        csr[pos] = (int)((v >> 8) << 7);          // src*128 bytes
    }
    for (int e = ebeg + t + EVC * 512; e < eend; e += 512) {
        unsigned int v = buck[e];
        int pos = atomicAdd(&curs[v & 255], 1);
        csr[pos] = (int)((v >> 8) << 7);
    }
}

// g0 = bf16(dinv[v] * x[v])
__global__ void g0_kernel(const float* __restrict__ x, const float* __restrict__ dinv,
                          unsigned short* __restrict__ g0) {
    int i = blockIdx.x * blockDim.x + threadIdx.x;
    if (i >= NN * HID / 4) return;
    float dv = dinv[(i * 4) >> 6];
    float4 v = *reinterpret_cast<const float4*>(&x[i * 4]);
    uint2 u;
    u.x = cvtpk(dv * v.x, dv * v.y);
    u.y = cvtpk(dv * v.z, dv * v.w);
    *reinterpret_cast<uint2*>(&g0[i * 4]) = u;
}

// ---------------- propagation ----------------
// One wave/node. grp=lane>>4 (4 edge slots), 16 lanes cover the 128B row (8B uint2/lane).
// Reduce = 2 shuffle stages x 4 accs. csr holds byte offsets (src*128).
template <int STEP>
__global__ void prop_kernel(const unsigned short* __restrict__ gin,
                            unsigned short* __restrict__ gout,
                            const unsigned short* __restrict__ g1,
                            const unsigned short* __restrict__ g2,
                            const float* __restrict__ x,
                            const float* __restrict__ dinv,
                            const float* __restrict__ rdinv,
                            const int* __restrict__ rowptr, const int* __restrict__ csr,
                            unsigned short* __restrict__ routb) {
    const int wid = (blockIdx.x * blockDim.x + threadIdx.x) >> 6;
    if (wid >= NN) return;
    const int lane = threadIdx.x & 63;
    const int grp = lane >> 4;                 // 4 edge slots
    const int fb  = (lane & 15) * 8;           // byte offset within 128B row
    const int beg = rowptr[wid], endp = rowptr[wid + 1];
    const float dv = dinv[wid];
    const char* gb = (const char*)gin;
    const int ob = wid * 128 + fb;             // self-row byte offset
    const uint2 qs = *(const uint2*)(gb + ob); // hoisted self row
    float a0 = 0.f, a1 = 0.f, a2 = 0.f, a3 = 0.f;
    int e = beg + grp;
    for (; e + 4 < endp; e += 8) {             // 8 edges per iter, 2-deep per group
        int c0 = csr[e], c1 = csr[e + 4];
        uint2 u0 = *(const uint2*)(gb + c0 + fb);
        uint2 u1 = *(const uint2*)(gb + c1 + fb);
        acc2(a0, a1, u0.x); acc2(a2, a3, u0.y);
        acc2(a0, a1, u1.x); acc2(a2, a3, u1.y);
    }
    if (e < endp) {
        int c0 = csr[e];
        uint2 u0 = *(const uint2*)(gb + c0 + fb);
        acc2(a0, a1, u0.x); acc2(a2, a3, u0.y);
    }
    a0 += __shfl_xor(a0, 16, 64); a0 += __shfl_xor(a0, 32, 64);
    a1 += __shfl_xor(a1, 16, 64); a1 += __shfl_xor(a1, 32, 64);
    a2 += __shfl_xor(a2, 16, 64); a2 += __shfl_xor(a2, 32, 64);
    a3 += __shfl_xor(a3, 16, 64); a3 += __shfl_xor(a3, 32, 64);
    if (grp != 0) return;
    float s0, s1, s2, s3;
    up2(s0, s1, qs.x); up2(s2, s3, qs.y);
    if (STEP < 2) {
        const float dv2 = dv * dv;
        uint2 gq;
        gq.x = cvtpk(dv2 * (a0 + s0), dv2 * (a1 + s1));
        gq.y = cvtpk(dv2 * (a2 + s2), dv2 * (a3 + s3));
        *(uint2*)((char*)gout + ob) = gq;
    } else {
        const float rd = rdinv[wid];           // sqrt(deg+1) = 1/dv
        uint2 b1 = *(const uint2*)((const char*)g1 + ob);
        uint2 b2 = *(const uint2*)((const char*)g2 + ob);
        float p0, p1, p2, p3, q0, q1, q2, q3;
        up2(p0, p1, b1.x); up2(p2, p3, b1.y);
        up2(q0, q1, b2.x); up2(q2, q3, b2.y);
        float4 xv = *reinterpret_cast<const float4*>(&x[wid * HID + (lane & 15) * 4]);
        float h0 = dv * (a0 + s0), h1 = dv * (a1 + s1);
        float h2 = dv * (a2 + s2), h3 = dv * (a3 + s3);
        float o0 = fmaxf(fmaf(ALPHA, xv.x, COEF * fmaf(rd, p0 + q0, h0)), 0.f);
        float o1 = fmaxf(fmaf(ALPHA, xv.y, COEF * fmaf(rd, p1 + q1, h1)), 0.f);
        float o2 = fmaxf(fmaf(ALPHA, xv.z, COEF * fmaf(rd, p2 + q2, h2)), 0.f);
        float o3 = fmaxf(fmaf(ALPHA, xv.w, COEF * fmaf(rd, p3 + q3, h3)), 0.f);
        uint2 r;
        r.x = cvtpk(o0, o1);
        r.y = cvtpk(o2, o3);
        *(uint2*)((char*)routb + ob) = r;
    }
}

// ---------------- SimpleConv(mean) of relu(out) + residual + relu ----------------
__global__ void final_kernel(const unsigned short* __restrict__ routb,
                             const float* __restrict__ x,
                             const int* __restrict__ rowptr, const int* __restrict__ csr,
                             float* __restrict__ res) {
    const int wid = (blockIdx.x * blockDim.x + threadIdx.x) >> 6;
    if (wid >= NN) return;
    const int lane = threadIdx.x & 63;
    const int grp = lane >> 4;
    const int fb  = (lane & 15) * 8;
    const int beg = rowptr[wid], endp = rowptr[wid + 1];
    const char* gb = (const char*)routb;
    float a0 = 0.f, a1 = 0.f, a2 = 0.f, a3 = 0.f;
    int e = beg + grp;
    for (; e + 4 < endp; e += 8) {
        int c0 = csr[e], c1 = csr[e + 4];
        uint2 u0 = *(const uint2*)(gb + c0 + fb);
        uint2 u1 = *(const uint2*)(gb + c1 + fb);
        acc2(a0, a1, u0.x); acc2(a2, a3, u0.y);
        acc2(a0, a1, u1.x); acc2(a2, a3, u1.y);
    }
    if (e < endp) {
        int c0 = csr[e];
        uint2 u0 = *(const uint2*)(gb + c0 + fb);
        acc2(a0, a1, u0.x); acc2(a2, a3, u0.y);
    }
    a0 += __shfl_xor(a0, 16, 64); a0 += __shfl_xor(a0, 32, 64);
    a1 += __shfl_xor(a1, 16, 64); a1 += __shfl_xor(a1, 32, 64);
    a2 += __shfl_xor(a2, 16, 64); a2 += __shfl_xor(a2, 32, 64);
    a3 += __shfl_xor(a3, 16, 64); a3 += __shfl_xor(a3, 32, 64);
    if (grp != 0) return;
    const float inv = 1.f / fmaxf((float)(endp - beg), 1.f);
    const int o = wid * HID + (lane & 15) * 4;
    float4 xv = *reinterpret_cast<const float4*>(&x[o]);
    float4 rv;
    rv.x = fmaxf(fmaf(a0, inv, xv.x), 0.f);
    rv.y = fmaxf(fmaf(a1, inv, xv.y), 0.f);
    rv.z = fmaxf(fmaf(a2, inv, xv.z), 0.f);
    rv.w = fmaxf(fmaf(a3, inv, xv.w), 0.f);
    *reinterpret_cast<float4*>(&res[o]) = rv;
}

extern "C" void kernel_launch(void* const* d_in, const int* in_sizes, int n_in,
                              void* d_out, int out_size, void* d_ws, size_t ws_size,
                              hipStream_t stream) {
    const float* x  = (const float*)d_in[0];
    const int* ei   = (const int*)d_in[1];      // (2, NE): [src | dst]
    const int* srcp = ei;
    const int* dstp = ei + NE;
    float* resp     = (float*)d_out;

    size_t off = 0;
    auto carve = [&](size_t bytes) { size_t p = off; off = (off + bytes + 255) & ~(size_t)255; return p; };
    char* ws = (char*)d_ws;
    int*          hist   = (int*)          (ws + carve((size_t)HTOT * 4));
    int*          hsum   = (int*)          (ws + carve((size_t)128 * 4));
    unsigned int* buck   = (unsigned int*) (ws + carve((size_t)NE * 4));
    int*          rowptr = (int*)          (ws + carve((size_t)(NN + 1) * 4));
    float*        dinv   = (float*)        (ws + carve((size_t)NN * 4));
    float*        rdinv  = (float*)        (ws + carve((size_t)NN * 4));
    int*          csr    = (int*)          (ws + carve((size_t)NE * 4));
    unsigned short* gA    = (unsigned short*)(ws + carve((size_t)NN * HID * 2));
    unsigned short* gB    = (unsigned short*)(ws + carve((size_t)NN * HID * 2));
    unsigned short* gC    = (unsigned short*)(ws + carve((size_t)NN * HID * 2));
    unsigned short* routb = (unsigned short*)(ws + carve((size_t)NN * HID * 2));
    (void)ws_size; (void)n_in; (void)in_sizes; (void)out_size;

    histA_kernel<<<SBLK, 256, 0, stream>>>(dstp, hist);
    scanHA_kernel<<<HTOT / 1024, 1024, 0, stream>>>(hist, hsum);
    scanHC_kernel<<<HTOT / 1024, 1024, 0, stream>>>(hist, hsum);
    scatterB_kernel<<<SBLK, 256, 0, stream>>>(srcp, dstp, hist, buck);
    bucketC_kernel<<<NBK, 512, 0, stream>>>(buck, hist, rowptr, dinv, rdinv, csr);
    g0_kernel<<<(NN * HID / 4 + 255) / 256, 256, 0, stream>>>(x, dinv, gA);

    const int nblk = 256;                            // 4 nodes/block (1 wave each)
    const int ngrid = (NN + 3) / 4;                  // 25000
    prop_kernel<0><<<ngrid, nblk, 0, stream>>>(gA, gB, nullptr, nullptr, nullptr, dinv, rdinv, rowptr, csr, nullptr);
    prop_kernel<1><<<ngrid, nblk, 0, stream>>>(gB, gC, nullptr, nullptr, nullptr, dinv, rdinv, rowptr, csr, nullptr);
    prop_kernel<2><<<ngrid, nblk, 0, stream>>>(gC, nullptr, gB, gC, x, dinv, rdinv, rowptr, csr, routb);
    final_kernel<<<ngrid, nblk, 0, stream>>>(routb, x, rowptr, csr, resp);
}

// Round 13
// 263.668 us; speedup vs baseline: 1.2534x; 1.1835x over previous
//
#include <hip/hip_runtime.h>
#include <hip/hip_bf16.h>

#define NN 100000
#define NE 1600000
#define HID 64
#define ALPHA 0.1f
#define COEF 0.3f   // (1-ALPHA)/K

#define NBK 392            // buckets of 256 nodes: dst>>8
#define SBLK 256           // blocks for hist/scatter passes (SBLK*NBK <= NE/16 keeps runs >= 1 line)
#define EB_PER_BLK (NE / SBLK)   // 6250
#define HTOT (NBK * SBLK)        // 100352 = 98 * 1024
#define EVC 12             // per-thread register edge cache in bucketC

// hardware packed f32->bf16 (RNE), 1 VALU op for 2 values
__device__ __forceinline__ unsigned int cvtpk(float lo, float hi) {
    unsigned int r;
    asm("v_cvt_pk_bf16_f32 %0, %1, %2" : "=v"(r) : "v"(lo), "v"(hi));
    return r;
}
// lo exact bf16; hi keeps low-16-bit mantissa contamination (<=1 ulp bf16) — saves the AND
__device__ __forceinline__ void acc2(float& lo, float& hi, unsigned int u) {
    union { unsigned int i; float f; } a, b;
    a.i = u << 16; b.i = u;
    lo += a.f; hi += b.f;
}
__device__ __forceinline__ void up2(float& lo, float& hi, unsigned int u) {
    union { unsigned int i; float f; } a, b;
    a.i = u << 16; b.i = u;
    lo = a.f; hi = b.f;
}

// ---------------- bucketed CSR build (no global atomics) ----------------

__global__ void histA_kernel(const int* __restrict__ dst, int* __restrict__ hist) {
    __shared__ int cnt[NBK];
    const int b = blockIdx.x, t = threadIdx.x;
    for (int i = t; i < NBK; i += 256) cnt[i] = 0;
    __syncthreads();
    const int beg = b * EB_PER_BLK, end = beg + EB_PER_BLK;
    for (int e = beg + t; e < end; e += 256)
        atomicAdd(&cnt[dst[e] >> 8], 1);
    __syncthreads();
    for (int i = t; i < NBK; i += 256)
        hist[i * SBLK + b] = cnt[i];
}

// coalesced 2-kernel scan of hist[HTOT]
__global__ void scanHA_kernel(const int* __restrict__ hist, int* __restrict__ hsum) {
    __shared__ int red[16];
    const int b = blockIdx.x, t = threadIdx.x;
    int v = hist[b * 1024 + t];
    for (int o = 32; o > 0; o >>= 1) v += __shfl_down(v, o, 64);
    if ((t & 63) == 0) red[t >> 6] = v;
    __syncthreads();
    if (t < 64) {
        int s = (t < 16) ? red[t] : 0;
        for (int o = 8; o > 0; o >>= 1) s += __shfl_down(s, o, 64);
        if (t == 0) hsum[b] = s;
    }
}

__global__ void scanHC_kernel(int* __restrict__ hist, const int* __restrict__ hsum) {
    __shared__ int ts[1024];
    __shared__ int s_off;
    const int b = blockIdx.x, t = threadIdx.x;
    int v = hist[b * 1024 + t];
    ts[t] = v;
    if (t == 0) {
        int o = 0;
        for (int i = 0; i < b; ++i) o += hsum[i];
        s_off = o;
    }
    __syncthreads();
    for (int off = 1; off < 1024; off <<= 1) {
        int w = (t >= off) ? ts[t - off] : 0;
        __syncthreads();
        if (t >= off) ts[t] += w;
        __syncthreads();
    }
    hist[b * 1024 + t] = s_off + ((t > 0) ? ts[t - 1] : 0);
}

__global__ void scatterB_kernel(const int* __restrict__ src, const int* __restrict__ dst,
                                const int* __restrict__ hist, unsigned int* __restrict__ buck) {
    __shared__ int cur[NBK];
    const int b = blockIdx.x, t = threadIdx.x;
    for (int i = t; i < NBK; i += 256) cur[i] = hist[i * SBLK + b];
    __syncthreads();
    const int beg = b * EB_PER_BLK, end = beg + EB_PER_BLK;
    for (int e = beg + t; e < end; e += 256) {
        int d = dst[e];
        int pos = atomicAdd(&cur[d >> 8], 1);
        buck[pos] = ((unsigned int)src[e] << 8) | (unsigned int)(d & 255);
    }
}

// Per-bucket (256 nodes, 512 thr): rowptr/dinv/rdinv + csr scatter from reg-cached edges.
// csr stores src*128 (byte offset of the bf16 row).
__global__ void bucketC_kernel(const unsigned int* __restrict__ buck, const int* __restrict__ hist,
                               int* __restrict__ rowptr, float* __restrict__ dinv,
                               float* __restrict__ rdinv, int* __restrict__ csr) {
    __shared__ int cnt[256];
    __shared__ int excl[256];
    __shared__ int curs[256];
    const int j = blockIdx.x, t = threadIdx.x;
    const int ebeg = hist[j * SBLK];
    const int eend = (j == NBK - 1) ? NE : hist[(j + 1) * SBLK];
    if (t < 256) cnt[t] = 0;
    __syncthreads();
    unsigned int ev[EVC];
    int m = 0;
    for (int e = ebeg + t; e < eend; e += 512) {
        unsigned int v = buck[e];
        atomicAdd(&cnt[v & 255], 1);
        if (m < EVC) ev[m++] = v;
    }
    __syncthreads();
    if (t < 256) excl[t] = cnt[t];
    __syncthreads();
    for (int off = 1; off < 256; off <<= 1) {
        int v = (t >= off && t < 256) ? excl[t - off] : 0;
        __syncthreads();
        if (t >= off && t < 256) excl[t] += v;
        __syncthreads();
    }
    if (t < 256) {
        const int my_excl = excl[t] - cnt[t];
        const int node = j * 256 + t;
        if (node < NN) {
            rowptr[node] = ebeg + my_excl;
            float sq = (float)(cnt[t] + 1);
            float dv = rsqrtf(sq);
            dinv[node]  = dv;
            rdinv[node] = sq * dv;     // sqrt(deg+1)
        }
        curs[t] = ebeg + my_excl;
    }
    if (j == NBK - 1 && t == 0) rowptr[NN] = NE;
    __syncthreads();
    for (int i = 0; i < m; ++i) {
        unsigned int v = ev[i];
        int pos = atomicAdd(&curs[v & 255], 1);
        csr[pos] = (int)((v >> 8) << 7);          // src*128 bytes
    }
    for (int e = ebeg + t + EVC * 512; e < eend; e += 512) {
        unsigned int v = buck[e];
        int pos = atomicAdd(&curs[v & 255], 1);
        csr[pos] = (int)((v >> 8) << 7);
    }
}

// g0 = bf16(dinv[v] * x[v])
__global__ void g0_kernel(const float* __restrict__ x, const float* __restrict__ dinv,
                          unsigned short* __restrict__ g0) {
    int i = blockIdx.x * blockDim.x + threadIdx.x;
    if (i >= NN * HID / 4) return;
    float dv = dinv[(i * 4) >> 6];
    float4 v = *reinterpret_cast<const float4*>(&x[i * 4]);
    uint2 u;
    u.x = cvtpk(dv * v.x, dv * v.y);
    u.y = cvtpk(dv * v.z, dv * v.w);
    *reinterpret_cast<uint2*>(&g0[i * 4]) = u;
}

// ---------------- propagation ----------------
// TWO nodes per wave: half=lane>>5 picks the node; within a half, grp=(lane>>3)&3
// gives 4 edge slots, 8 lanes x uint4(16B) cover the 128B row. Gathers stay 1KB/instr.
// Reduce = 2 shuffle stages (xor 8, 16) within the half. csr holds byte offsets.
template <int STEP>
__global__ void prop_kernel(const unsigned short* __restrict__ gin,
                            unsigned short* __restrict__ gout,
                            const unsigned short* __restrict__ g1,
                            const unsigned short* __restrict__ g2,
                            const float* __restrict__ x,
                            const float* __restrict__ dinv,
                            const float* __restrict__ rdinv,
                            const int* __restrict__ rowptr, const int* __restrict__ csr,
                            unsigned short* __restrict__ routb) {
    const int wp = (blockIdx.x * blockDim.x + threadIdx.x) >> 6;   // wave-pair id
    if (wp >= NN / 2) return;
    const int lane = threadIdx.x & 63;
    const int half = lane >> 5;
    const int node = wp * 2 + half;
    const int grp  = (lane >> 3) & 3;          // 4 edge slots per half
    const int fb   = (lane & 7) * 16;          // byte offset within 128B row
    const int beg = rowptr[node], endp = rowptr[node + 1];
    const float dv = dinv[node];
    const char* gb = (const char*)gin;
    const int ob = node * 128 + fb;            // self-row byte offset
    const uint4 qs = *(const uint4*)(gb + ob); // hoisted self row
    float a[8];
#pragma unroll
    for (int i = 0; i < 8; ++i) a[i] = 0.f;
    int e = beg + grp;
    for (; e + 4 < endp; e += 8) {             // 8 edges/half-iter, 2 gathers in flight
        int c0 = csr[e], c1 = csr[e + 4];
        uint4 u0 = *(const uint4*)(gb + c0 + fb);
        uint4 u1 = *(const uint4*)(gb + c1 + fb);
        acc2(a[0], a[1], u0.x); acc2(a[2], a[3], u0.y);
        acc2(a[4], a[5], u0.z); acc2(a[6], a[7], u0.w);
        acc2(a[0], a[1], u1.x); acc2(a[2], a[3], u1.y);
        acc2(a[4], a[5], u1.z); acc2(a[6], a[7], u1.w);
    }
    if (e < endp) {
        int c0 = csr[e];
        uint4 u0 = *(const uint4*)(gb + c0 + fb);
        acc2(a[0], a[1], u0.x); acc2(a[2], a[3], u0.y);
        acc2(a[4], a[5], u0.z); acc2(a[6], a[7], u0.w);
    }
#pragma unroll
    for (int i = 0; i < 8; ++i) {              // reduce over 4 groups (within half)
        a[i] += __shfl_xor(a[i], 8, 64);
        a[i] += __shfl_xor(a[i], 16, 64);
    }
    if (grp != 0) return;                      // lanes 0-7 and 32-39 continue
    float s[8];
    up2(s[0], s[1], qs.x); up2(s[2], s[3], qs.y);
    up2(s[4], s[5], qs.z); up2(s[6], s[7], qs.w);
    if (STEP < 2) {
        const float dv2 = dv * dv;
        uint4 gq;
        gq.x = cvtpk(dv2 * (a[0] + s[0]), dv2 * (a[1] + s[1]));
        gq.y = cvtpk(dv2 * (a[2] + s[2]), dv2 * (a[3] + s[3]));
        gq.z = cvtpk(dv2 * (a[4] + s[4]), dv2 * (a[5] + s[5]));
        gq.w = cvtpk(dv2 * (a[6] + s[6]), dv2 * (a[7] + s[7]));
        *(uint4*)((char*)gout + ob) = gq;
    } else {
        const float rd = rdinv[node];          // sqrt(deg+1) = 1/dv
        uint4 b1 = *(const uint4*)((const char*)g1 + ob);
        uint4 b2 = *(const uint4*)((const char*)g2 + ob);
        float p[8], q[8];
        up2(p[0], p[1], b1.x); up2(p[2], p[3], b1.y);
        up2(p[4], p[5], b1.z); up2(p[6], p[7], b1.w);
        up2(q[0], q[1], b2.x); up2(q[2], q[3], b2.y);
        up2(q[4], q[5], b2.z); up2(q[6], q[7], b2.w);
        const int xo = node * HID + (lane & 7) * 8;
        float4 x0 = *reinterpret_cast<const float4*>(&x[xo]);
        float4 x1 = *reinterpret_cast<const float4*>(&x[xo + 4]);
        float xr[8] = {x0.x, x0.y, x0.z, x0.w, x1.x, x1.y, x1.z, x1.w};
        float ov[8];
#pragma unroll
        for (int i = 0; i < 8; ++i) {
            float h = dv * (a[i] + s[i]);
            ov[i] = fmaxf(fmaf(ALPHA, xr[i], COEF * fmaf(rd, p[i] + q[i], h)), 0.f);
        }
        uint4 r;
        r.x = cvtpk(ov[0], ov[1]); r.y = cvtpk(ov[2], ov[3]);
        r.z = cvtpk(ov[4], ov[5]); r.w = cvtpk(ov[6], ov[7]);
        *(uint4*)((char*)routb + ob) = r;
    }
}

// ---------------- SimpleConv(mean) of relu(out) + residual + relu ----------------
__global__ void final_kernel(const unsigned short* __restrict__ routb,
                             const float* __restrict__ x,
                             const int* __restrict__ rowptr, const int* __restrict__ csr,
                             float* __restrict__ res) {
    const int wp = (blockIdx.x * blockDim.x + threadIdx.x) >> 6;
    if (wp >= NN / 2) return;
    const int lane = threadIdx.x & 63;
    const int half = lane >> 5;
    const int node = wp * 2 + half;
    const int grp  = (lane >> 3) & 3;
    const int fb   = (lane & 7) * 16;
    const int beg = rowptr[node], endp = rowptr[node + 1];
    const char* gb = (const char*)routb;
    float a[8];
#pragma unroll
    for (int i = 0; i < 8; ++i) a[i] = 0.f;
    int e = beg + grp;
    for (; e + 4 < endp; e += 8) {
        int c0 = csr[e], c1 = csr[e + 4];
        uint4 u0 = *(const uint4*)(gb + c0 + fb);
        uint4 u1 = *(const uint4*)(gb + c1 + fb);
        acc2(a[0], a[1], u0.x); acc2(a[2], a[3], u0.y);
        acc2(a[4], a[5], u0.z); acc2(a[6], a[7], u0.w);
        acc2(a[0], a[1], u1.x); acc2(a[2], a[3], u1.y);
        acc2(a[4], a[5], u1.z); acc2(a[6], a[7], u1.w);
    }
    if (e < endp) {
        int c0 = csr[e];
        uint4 u0 = *(const uint4*)(gb + c0 + fb);
        acc2(a[0], a[1], u0.x); acc2(a[2], a[3], u0.y);
        acc2(a[4], a[5], u0.z); acc2(a[6], a[7], u0.w);
    }
#pragma unroll
    for (int i = 0; i < 8; ++i) {
        a[i] += __shfl_xor(a[i], 8, 64);
        a[i] += __shfl_xor(a[i], 16, 64);
    }
    if (grp != 0) return;
    const float inv = 1.f / fmaxf((float)(endp - beg), 1.f);
    const int xo = node * HID + (lane & 7) * 8;
    float4 x0 = *reinterpret_cast<const float4*>(&x[xo]);
    float4 x1 = *reinterpret_cast<const float4*>(&x[xo + 4]);
    float4 r0, r1;
    r0.x = fmaxf(fmaf(a[0], inv, x0.x), 0.f); r0.y = fmaxf(fmaf(a[1], inv, x0.y), 0.f);
    r0.z = fmaxf(fmaf(a[2], inv, x0.z), 0.f); r0.w = fmaxf(fmaf(a[3], inv, x0.w), 0.f);
    r1.x = fmaxf(fmaf(a[4], inv, x1.x), 0.f); r1.y = fmaxf(fmaf(a[5], inv, x1.y), 0.f);
    r1.z = fmaxf(fmaf(a[6], inv, x1.z), 0.f); r1.w = fmaxf(fmaf(a[7], inv, x1.w), 0.f);
    *reinterpret_cast<float4*>(&res[xo])     = r0;
    *reinterpret_cast<float4*>(&res[xo + 4]) = r1;
}

extern "C" void kernel_launch(void* const* d_in, const int* in_sizes, int n_in,
                              void* d_out, int out_size, void* d_ws, size_t ws_size,
                              hipStream_t stream) {
    const float* x  = (const float*)d_in[0];
    const int* ei   = (const int*)d_in[1];      // (2, NE): [src | dst]
    const int* srcp = ei;
    const int* dstp = ei + NE;
    float* resp     = (float*)d_out;

    size_t off = 0;
    auto carve = [&](size_t bytes) { size_t p = off; off = (off + bytes + 255) & ~(size_t)255; return p; };
    char* ws = (char*)d_ws;
    int*          hist   = (int*)          (ws + carve((size_t)HTOT * 4));
    int*          hsum   = (int*)          (ws + carve((size_t)128 * 4));
    unsigned int* buck   = (unsigned int*) (ws + carve((size_t)NE * 4));
    int*          rowptr = (int*)          (ws + carve((size_t)(NN + 1) * 4));
    float*        dinv   = (float*)        (ws + carve((size_t)NN * 4));
    float*        rdinv  = (float*)        (ws + carve((size_t)NN * 4));
    int*          csr    = (int*)          (ws + carve((size_t)NE * 4));
    unsigned short* gA    = (unsigned short*)(ws + carve((size_t)NN * HID * 2));
    unsigned short* gB    = (unsigned short*)(ws + carve((size_t)NN * HID * 2));
    unsigned short* gC    = (unsigned short*)(ws + carve((size_t)NN * HID * 2));
    unsigned short* routb = (unsigned short*)(ws + carve((size_t)NN * HID * 2));
    (void)ws_size; (void)n_in; (void)in_sizes; (void)out_size;

    histA_kernel<<<SBLK, 256, 0, stream>>>(dstp, hist);
    scanHA_kernel<<<HTOT / 1024, 1024, 0, stream>>>(hist, hsum);
    scanHC_kernel<<<HTOT / 1024, 1024, 0, stream>>>(hist, hsum);
    scatterB_kernel<<<SBLK, 256, 0, stream>>>(srcp, dstp, hist, buck);
    bucketC_kernel<<<NBK, 512, 0, stream>>>(buck, hist, rowptr, dinv, rdinv, csr);
    g0_kernel<<<(NN * HID / 4 + 255) / 256, 256, 0, stream>>>(x, dinv, gA);

    const int nblk = 256;                            // 4 waves/block, 2 nodes/wave
    const int ngrid = (NN / 2 + 3) / 4;              // 12500
    prop_kernel<0><<<ngrid, nblk, 0, stream>>>(gA, gB, nullptr, nullptr, nullptr, dinv, rdinv, rowptr, csr, nullptr);
    prop_kernel<1><<<ngrid, nblk, 0, stream>>>(gB, gC, nullptr, nullptr, nullptr, dinv, rdinv, rowptr, csr, nullptr);
    prop_kernel<2><<<ngrid, nblk, 0, stream>>>(gC, nullptr, gB, gC, x, dinv, rdinv, rowptr, csr, routb);
    final_kernel<<<ngrid, nblk, 0, stream>>>(routb, x, rowptr, csr, resp);
}

// Round 15
// 262.094 us; speedup vs baseline: 1.2610x; 1.0060x over previous
//
#include <hip/hip_runtime.h>
#include <hip/hip_fp16.h>

#define NN 100000
#define NE 1600000
#define HID 64
#define ALPHA 0.1f
#define COEF 0.3f   // (1-ALPHA)/K

#define NBK 392            // buckets of 256 nodes: dst>>8
#define SBLK 256           // blocks for hist/scatter passes (SBLK*NBK <= NE/16 keeps runs >= 1 line)
#define EB_PER_BLK (NE / SBLK)   // 6250
#define HTOT (NBK * SBLK)        // 100352 = 98 * 1024
#define EVC 12             // per-thread register edge cache in bucketC

// packed f32 pair -> fp16 pair (RTZ), 1 VALU op
__device__ __forceinline__ unsigned int pkrtz(float lo, float hi) {
    unsigned int r;
    asm("v_cvt_pkrtz_f16_f32 %0, %1, %2" : "=v"(r) : "v"(lo), "v"(hi));
    return r;
}
__device__ __forceinline__ __half2 u2h(unsigned int u) {
    union { unsigned int i; __half2 h; } v; v.i = u; return v.h;
}
__device__ __forceinline__ unsigned int h2u(__half2 h) {
    union { unsigned int i; __half2 h; } v; v.h = h; return v.i;
}

// ---------------- bucketed CSR build (no global atomics) ----------------

__global__ void histA_kernel(const int* __restrict__ dst, int* __restrict__ hist) {
    __shared__ int cnt[NBK];
    const int b = blockIdx.x, t = threadIdx.x;
    for (int i = t; i < NBK; i += 256) cnt[i] = 0;
    __syncthreads();
    const int beg = b * EB_PER_BLK, end = beg + EB_PER_BLK;
    for (int e = beg + t; e < end; e += 256)
        atomicAdd(&cnt[dst[e] >> 8], 1);
    __syncthreads();
    for (int i = t; i < NBK; i += 256)
        hist[i * SBLK + b] = cnt[i];
}

// coalesced 2-kernel scan of hist[HTOT]
__global__ void scanHA_kernel(const int* __restrict__ hist, int* __restrict__ hsum) {
    __shared__ int red[16];
    const int b = blockIdx.x, t = threadIdx.x;
    int v = hist[b * 1024 + t];
    for (int o = 32; o > 0; o >>= 1) v += __shfl_down(v, o, 64);
    if ((t & 63) == 0) red[t >> 6] = v;
    __syncthreads();
    if (t < 64) {
        int s = (t < 16) ? red[t] : 0;
        for (int o = 8; o > 0; o >>= 1) s += __shfl_down(s, o, 64);
        if (t == 0) hsum[b] = s;
    }
}

__global__ void scanHC_kernel(int* __restrict__ hist, const int* __restrict__ hsum) {
    __shared__ int ts[1024];
    __shared__ int s_off;
    const int b = blockIdx.x, t = threadIdx.x;
    int v = hist[b * 1024 + t];
    ts[t] = v;
    if (t == 0) {
        int o = 0;
        for (int i = 0; i < b; ++i) o += hsum[i];
        s_off = o;
    }
    __syncthreads();
    for (int off = 1; off < 1024; off <<= 1) {
        int w = (t >= off) ? ts[t - off] : 0;
        __syncthreads();
        if (t >= off) ts[t] += w;
        __syncthreads();
    }
    hist[b * 1024 + t] = s_off + ((t > 0) ? ts[t - 1] : 0);
}

__global__ void scatterB_kernel(const int* __restrict__ src, const int* __restrict__ dst,
                                const int* __restrict__ hist, unsigned int* __restrict__ buck) {
    __shared__ int cur[NBK];
    const int b = blockIdx.x, t = threadIdx.x;
    for (int i = t; i < NBK; i += 256) cur[i] = hist[i * SBLK + b];
    __syncthreads();
    const int beg = b * EB_PER_BLK, end = beg + EB_PER_BLK;
    for (int e = beg + t; e < end; e += 256) {
        int d = dst[e];
        int pos = atomicAdd(&cur[d >> 8], 1);
        buck[pos] = ((unsigned int)src[e] << 8) | (unsigned int)(d & 255);
    }
}

// Per-bucket (256 nodes, 512 thr): rowptr/dinv/rdinv + csr scatter from reg-cached edges.
// csr stores src*128 (byte offset of the fp16 row).
__global__ void bucketC_kernel(const unsigned int* __restrict__ buck, const int* __restrict__ hist,
                               int* __restrict__ rowptr, float* __restrict__ dinv,
                               float* __restrict__ rdinv, int* __restrict__ csr) {
    __shared__ int cnt[256];
    __shared__ int excl[256];
    __shared__ int curs[256];
    const int j = blockIdx.x, t = threadIdx.x;
    const int ebeg = hist[j * SBLK];
    const int eend = (j == NBK - 1) ? NE : hist[(j + 1) * SBLK];
    if (t < 256) cnt[t] = 0;
    __syncthreads();
    unsigned int ev[EVC];
    int m = 0;
    for (int e = ebeg + t; e < eend; e += 512) {
        unsigned int v = buck[e];
        atomicAdd(&cnt[v & 255], 1);
        if (m < EVC) ev[m++] = v;
    }
    __syncthreads();
    if (t < 256) excl[t] = cnt[t];
    __syncthreads();
    for (int off = 1; off < 256; off <<= 1) {
        int v = (t >= off && t < 256) ? excl[t - off] : 0;
        __syncthreads();
        if (t >= off && t < 256) excl[t] += v;
        __syncthreads();
    }
    if (t < 256) {
        const int my_excl = excl[t] - cnt[t];
        const int node = j * 256 + t;
        if (node < NN) {
            rowptr[node] = ebeg + my_excl;
            float sq = (float)(cnt[t] + 1);
            float dv = rsqrtf(sq);
            dinv[node]  = dv;
            rdinv[node] = sq * dv;     // sqrt(deg+1)
        }
        curs[t] = ebeg + my_excl;
    }
    if (j == NBK - 1 && t == 0) rowptr[NN] = NE;
    __syncthreads();
    for (int i = 0; i < m; ++i) {
        unsigned int v = ev[i];
        int pos = atomicAdd(&curs[v & 255], 1);
        csr[pos] = (int)((v >> 8) << 7);          // src*128 bytes
    }
    for (int e = ebeg + t + EVC * 512; e < eend; e += 512) {
        unsigned int v = buck[e];
        int pos = atomicAdd(&curs[v & 255], 1);
        csr[pos] = (int)((v >> 8) << 7);
    }
}

// g0 = fp16(dinv[v] * x[v])
__global__ void g0_kernel(const float* __restrict__ x, const float* __restrict__ dinv,
                          unsigned short* __restrict__ g0) {
    int i = blockIdx.x * blockDim.x + threadIdx.x;
    if (i >= NN * HID / 4) return;
    float dv = dinv[(i * 4) >> 6];
    float4 v = *reinterpret_cast<const float4*>(&x[i * 4]);
    uint2 u;
    u.x = pkrtz(dv * v.x, dv * v.y);
    u.y = pkrtz(dv * v.z, dv * v.w);
    *reinterpret_cast<uint2*>(&g0[i * 4]) = u;
}

// ---------------- propagation (fp16 storage, packed fp16 accumulate) ----------------
// TWO nodes per wave: half=lane>>5 picks the node; grp=(lane>>3)&3 gives 4 edge slots,
// 8 lanes x uint4(16B) cover the 128B row. Reduce = 2 packed shuffle stages.
template <int STEP>
__global__ void prop_kernel(const unsigned short* __restrict__ gin,
                            unsigned short* __restrict__ gout,
                            const unsigned short* __restrict__ g1,
                            const unsigned short* __restrict__ g2,
                            const float* __restrict__ x,
                            const float* __restrict__ dinv,
                            const float* __restrict__ rdinv,
                            const int* __restrict__ rowptr, const int* __restrict__ csr,
                            unsigned short* __restrict__ routb) {
    const int wp = (blockIdx.x * blockDim.x + threadIdx.x) >> 6;   // wave-pair id
    if (wp >= NN / 2) return;
    const int lane = threadIdx.x & 63;
    const int half = lane >> 5;
    const int node = wp * 2 + half;
    const int grp  = (lane >> 3) & 3;          // 4 edge slots per half
    const int fb   = (lane & 7) * 16;          // byte offset within 128B row
    const int beg = rowptr[node], endp = rowptr[node + 1];
    const float dv = dinv[node];
    const char* gb = (const char*)gin;
    const int ob = node * 128 + fb;            // self-row byte offset
    const uint4 qs = *(const uint4*)(gb + ob); // hoisted self row
    __half2 a0 = u2h(0u), a1 = u2h(0u), a2 = u2h(0u), a3 = u2h(0u);
    int e = beg + grp;
    for (; e + 4 < endp; e += 8) {             // 8 edges/half-iter, 2 gathers in flight
        int c0 = csr[e], c1 = csr[e + 4];
        uint4 u0 = *(const uint4*)(gb + c0 + fb);
        uint4 u1 = *(const uint4*)(gb + c1 + fb);
        a0 = __hadd2(a0, u2h(u0.x)); a1 = __hadd2(a1, u2h(u0.y));
        a2 = __hadd2(a2, u2h(u0.z)); a3 = __hadd2(a3, u2h(u0.w));
        a0 = __hadd2(a0, u2h(u1.x)); a1 = __hadd2(a1, u2h(u1.y));
        a2 = __hadd2(a2, u2h(u1.z)); a3 = __hadd2(a3, u2h(u1.w));
    }
    if (e < endp) {
        int c0 = csr[e];
        uint4 u0 = *(const uint4*)(gb + c0 + fb);
        a0 = __hadd2(a0, u2h(u0.x)); a1 = __hadd2(a1, u2h(u0.y));
        a2 = __hadd2(a2, u2h(u0.z)); a3 = __hadd2(a3, u2h(u0.w));
    }
    // packed cross-group reduce (xor 8, 16 within the half)
    a0 = __hadd2(a0, u2h(__shfl_xor(h2u(a0), 8, 64)));
    a1 = __hadd2(a1, u2h(__shfl_xor(h2u(a1), 8, 64)));
    a2 = __hadd2(a2, u2h(__shfl_xor(h2u(a2), 8, 64)));
    a3 = __hadd2(a3, u2h(__shfl_xor(h2u(a3), 8, 64)));
    a0 = __hadd2(a0, u2h(__shfl_xor(h2u(a0), 16, 64)));
    a1 = __hadd2(a1, u2h(__shfl_xor(h2u(a1), 16, 64)));
    a2 = __hadd2(a2, u2h(__shfl_xor(h2u(a2), 16, 64)));
    a3 = __hadd2(a3, u2h(__shfl_xor(h2u(a3), 16, 64)));
    if (grp != 0) return;                      // lanes 0-7 and 32-39 continue
    // add self row (packed)
    a0 = __hadd2(a0, u2h(qs.x)); a1 = __hadd2(a1, u2h(qs.y));
    a2 = __hadd2(a2, u2h(qs.z)); a3 = __hadd2(a3, u2h(qs.w));
    if (STEP < 2) {
        const __half2 dv2h = __float2half2_rn(dv * dv);
        uint4 gq;
        gq.x = h2u(__hmul2(a0, dv2h)); gq.y = h2u(__hmul2(a1, dv2h));
        gq.z = h2u(__hmul2(a2, dv2h)); gq.w = h2u(__hmul2(a3, dv2h));
        *(uint4*)((char*)gout + ob) = gq;
    } else {
        const float rd = rdinv[node];          // sqrt(deg+1) = 1/dv
        uint4 b1 = *(const uint4*)((const char*)g1 + ob);
        uint4 b2 = *(const uint4*)((const char*)g2 + ob);
        float2 f0 = __half22float2(a0), f1 = __half22float2(a1);
        float2 f2 = __half22float2(a2), f3 = __half22float2(a3);
        float2 p0 = __half22float2(u2h(b1.x)), p1 = __half22float2(u2h(b1.y));
        float2 p2 = __half22float2(u2h(b1.z)), p3 = __half22float2(u2h(b1.w));
        float2 q0 = __half22float2(u2h(b2.x)), q1 = __half22float2(u2h(b2.y));
        float2 q2 = __half22float2(u2h(b2.z)), q3 = __half22float2(u2h(b2.w));
        const int xo = node * HID + (lane & 7) * 8;
        float4 x0 = *reinterpret_cast<const float4*>(&x[xo]);
        float4 x1 = *reinterpret_cast<const float4*>(&x[xo + 4]);
        float hh[8] = {f0.x, f0.y, f1.x, f1.y, f2.x, f2.y, f3.x, f3.y};
        float pp[8] = {p0.x, p0.y, p1.x, p1.y, p2.x, p2.y, p3.x, p3.y};
        float qq[8] = {q0.x, q0.y, q1.x, q1.y, q2.x, q2.y, q3.x, q3.y};
        float xr[8] = {x0.x, x0.y, x0.z, x0.w, x1.x, x1.y, x1.z, x1.w};
        float ov[8];
#pragma unroll
        for (int i = 0; i < 8; ++i) {
            float h = dv * hh[i];
            ov[i] = fmaxf(fmaf(ALPHA, xr[i], COEF * fmaf(rd, pp[i] + qq[i], h)), 0.f);
        }
        uint4 r;
        r.x = pkrtz(ov[0], ov[1]); r.y = pkrtz(ov[2], ov[3]);
        r.z = pkrtz(ov[4], ov[5]); r.w = pkrtz(ov[6], ov[7]);
        *(uint4*)((char*)routb + ob) = r;
    }
}

// ---------------- SimpleConv(mean) of relu(out) + residual + relu ----------------
__global__ void final_kernel(const unsigned short* __restrict__ routb,
                             const float* __restrict__ x,
                             const int* __restrict__ rowptr, const int* __restrict__ csr,
                             float* __restrict__ res) {
    const int wp = (blockIdx.x * blockDim.x + threadIdx.x) >> 6;
    if (wp >= NN / 2) return;
    const int lane = threadIdx.x & 63;
    const int half = lane >> 5;
    const int node = wp * 2 + half;
    const int grp  = (lane >> 3) & 3;
    const int fb   = (lane & 7) * 16;
    const int beg = rowptr[node], endp = rowptr[node + 1];
    const char* gb = (const char*)routb;
    __half2 a0 = u2h(0u), a1 = u2h(0u), a2 = u2h(0u), a3 = u2h(0u);
    int e = beg + grp;
    for (; e + 4 < endp; e += 8) {
        int c0 = csr[e], c1 = csr[e + 4];
        uint4 u0 = *(const uint4*)(gb + c0 + fb);
        uint4 u1 = *(const uint4*)(gb + c1 + fb);
        a0 = __hadd2(a0, u2h(u0.x)); a1 = __hadd2(a1, u2h(u0.y));
        a2 = __hadd2(a2, u2h(u0.z)); a3 = __hadd2(a3, u2h(u0.w));
        a0 = __hadd2(a0, u2h(u1.x)); a1 = __hadd2(a1, u2h(u1.y));
        a2 = __hadd2(a2, u2h(u1.z)); a3 = __hadd2(a3, u2h(u1.w));
    }
    if (e < endp) {
        int c0 = csr[e];
        uint4 u0 = *(const uint4*)(gb + c0 + fb);
        a0 = __hadd2(a0, u2h(u0.x)); a1 = __hadd2(a1, u2h(u0.y));
        a2 = __hadd2(a2, u2h(u0.z)); a3 = __hadd2(a3, u2h(u0.w));
    }
    a0 = __hadd2(a0, u2h(__shfl_xor(h2u(a0), 8, 64)));
    a1 = __hadd2(a1, u2h(__shfl_xor(h2u(a1), 8, 64)));
    a2 = __hadd2(a2, u2h(__shfl_xor(h2u(a2), 8, 64)));
    a3 = __hadd2(a3, u2h(__shfl_xor(h2u(a3), 8, 64)));
    a0 = __hadd2(a0, u2h(__shfl_xor(h2u(a0), 16, 64)));
    a1 = __hadd2(a1, u2h(__shfl_xor(h2u(a1), 16, 64)));
    a2 = __hadd2(a2, u2h(__shfl_xor(h2u(a2), 16, 64)));
    a3 = __hadd2(a3, u2h(__shfl_xor(h2u(a3), 16, 64)));
    if (grp != 0) return;
    const float inv = 1.f / fmaxf((float)(endp - beg), 1.f);
    float2 f0 = __half22float2(a0), f1 = __half22float2(a1);
    float2 f2 = __half22float2(a2), f3 = __half22float2(a3);
    float aa[8] = {f0.x, f0.y, f1.x, f1.y, f2.x, f2.y, f3.x, f3.y};
    const int xo = node * HID + (lane & 7) * 8;
    float4 x0 = *reinterpret_cast<const float4*>(&x[xo]);
    float4 x1 = *reinterpret_cast<const float4*>(&x[xo + 4]);
    float xr[8] = {x0.x, x0.y, x0.z, x0.w, x1.x, x1.y, x1.z, x1.w};
    float rv[8];
#pragma unroll
    for (int i = 0; i < 8; ++i) rv[i] = fmaxf(fmaf(aa[i], inv, xr[i]), 0.f);
    float4 r0 = {rv[0], rv[1], rv[2], rv[3]};
    float4 r1 = {rv[4], rv[5], rv[6], rv[7]};
    *reinterpret_cast<float4*>(&res[xo])     = r0;
    *reinterpret_cast<float4*>(&res[xo + 4]) = r1;
}

extern "C" void kernel_launch(void* const* d_in, const int* in_sizes, int n_in,
                              void* d_out, int out_size, void* d_ws, size_t ws_size,
                              hipStream_t stream) {
    const float* x  = (const float*)d_in[0];
    const int* ei   = (const int*)d_in[1];      // (2, NE): [src | dst]
    const int* srcp = ei;
    const int* dstp = ei + NE;
    float* resp     = (float*)d_out;

    size_t off = 0;
    auto carve = [&](size_t bytes) { size_t p = off; off = (off + bytes + 255) & ~(size_t)255; return p; };
    char* ws = (char*)d_ws;
    int*          hist   = (int*)          (ws + carve((size_t)HTOT * 4));
    int*          hsum   = (int*)          (ws + carve((size_t)128 * 4));
    unsigned int* buck   = (unsigned int*) (ws + carve((size_t)NE * 4));
    int*          rowptr = (int*)          (ws + carve((size_t)(NN + 1) * 4));
    float*        dinv   = (float*)        (ws + carve((size_t)NN * 4));
    float*        rdinv  = (float*)        (ws + carve((size_t)NN * 4));
    int*          csr    = (int*)          (ws + carve((size_t)NE * 4));
    unsigned short* gA    = (unsigned short*)(ws + carve((size_t)NN * HID * 2));
    unsigned short* gB    = (unsigned short*)(ws + carve((size_t)NN * HID * 2));
    unsigned short* gC    = (unsigned short*)(ws + carve((size_t)NN * HID * 2));
    unsigned short* routb = (unsigned short*)(ws + carve((size_t)NN * HID * 2));
    (void)ws_size; (void)n_in; (void)in_sizes; (void)out_size;

    histA_kernel<<<SBLK, 256, 0, stream>>>(dstp, hist);
    scanHA_kernel<<<HTOT / 1024, 1024, 0, stream>>>(hist, hsum);
    scanHC_kernel<<<HTOT / 1024, 1024, 0, stream>>>(hist, hsum);
    scatterB_kernel<<<SBLK, 256, 0, stream>>>(srcp, dstp, hist, buck);
    bucketC_kernel<<<NBK, 512, 0, stream>>>(buck, hist, rowptr, dinv, rdinv, csr);
    g0_kernel<<<(NN * HID / 4 + 255) / 256, 256, 0, stream>>>(x, dinv, gA);

    const int nblk = 256;                            // 4 waves/block, 2 nodes/wave
    const int ngrid = (NN / 2 + 3) / 4;              // 12500
    prop_kernel<0><<<ngrid, nblk, 0, stream>>>(gA, gB, nullptr, nullptr, nullptr, dinv, rdinv, rowptr, csr, nullptr);
    prop_kernel<1><<<ngrid, nblk, 0, stream>>>(gB, gC, nullptr, nullptr, nullptr, dinv, rdinv, rowptr, csr, nullptr);
    prop_kernel<2><<<ngrid, nblk, 0, stream>>>(gC, nullptr, gB, gC, x, dinv, rdinv, rowptr, csr, routb);
    final_kernel<<<ngrid, nblk, 0, stream>>>(routb, x, rowptr, csr, resp);
}